// Round 3
// baseline (1159.515 us; speedup 1.0000x reference)
//
#include <hip/hip_runtime.h>

// AR LSTM decoder, B=256, T=2048, IN=64, H=32, NCLS=5.
//
// R7: remove LDS from the recurrence critical path.
//   - h broadcast via 32x v_readlane into SGPRs (h[m] identical in lanes
//     2m/2m+1); W_hh matvec + classifier consume h as the SGPR operand of
//     v_fmac_f32. Replaces s_hd write + 8x ds_read_b128 + waits (~450 cy
//     exposed under 128-VGPR pressure) with ~10 cy of readlane latency.
//   - accumulation mapped chain-exactly onto R6's f2 chains (chain
//     k=(m>>1)&3, comp m&1, same visit order, same combine tree) ->
//     bit-identical results.
//   - log-softmax + store offloaded to the (80% idle) producer wave via a
//     full-length LDS ring of raw logits (2047x5 f32, 41 KB). Availability
//     signaled by the existing s_cons release (release/acquire already
//     orders the ring writes). Producer reproduces exact max/sum order.
// Producer gx pipeline: verbatim from the proven kernel.

namespace {

typedef float f2 __attribute__((ext_vector_type(2)));
typedef unsigned int u32;
typedef const __attribute__((address_space(1))) u32* gas_ptr;
typedef __attribute__((address_space(3))) u32* las_ptr;

constexpr int Tn  = 2048;
constexpr int INn = 64;
constexpr int Hn  = 32;
constexpr int NC  = 5;
constexpr int CH  = 32;            // steps per chunk
constexpr int CHF = CH * INn;      // 2048 floats x-chunk (8 KB)
constexpr int GXF = CH * 128;      // 4096 floats gx-chunk (16 KB)
constexpr int NCHUNK = Tn / CH;    // 64
constexpr int RING = Tn - 1;       // rows 0..2046 via ring; row 2047 direct

__device__ __forceinline__ float rcpf(float x) { return __builtin_amdgcn_rcpf(x); }
__device__ __forceinline__ float hadd(f2 v) { return v.x + v.y; }

__device__ __forceinline__ float rlane(float x, int l) {
    return __int_as_float(__builtin_amdgcn_readlane(__float_as_int(x), l));
}

__device__ __forceinline__ float dpp_swap1(float x) {   // quad_perm xor 1
    int t = __builtin_amdgcn_update_dpp(0, __float_as_int(x), 0xB1, 0xF, 0xF, true);
    return __int_as_float(t);
}

__device__ __forceinline__ void gl16(const float* g, float* l) {
    __builtin_amdgcn_global_load_lds((gas_ptr)g, (las_ptr)l, 16, 0, 0);
}

__device__ __forceinline__ int ld_acq(int* p) {
    return __hip_atomic_load(p, __ATOMIC_ACQUIRE, __HIP_MEMORY_SCOPE_WORKGROUP);
}
__device__ __forceinline__ void st_rel(int* p, int v) {
    __hip_atomic_store(p, v, __ATOMIC_RELEASE, __HIP_MEMORY_SCOPE_WORKGROUP);
}

__global__ __launch_bounds__(128, 1)
void ar_decode(const float* __restrict__ x,
               const float* __restrict__ W_ih,
               const float* __restrict__ W_hh,
               const float* __restrict__ b_ih,
               const float* __restrict__ b_hh,
               const float* __restrict__ W_fc,
               const float* __restrict__ b_fc,
               const float* __restrict__ emb,
               float* __restrict__ out)
{
    const int b    = blockIdx.x;
    const int tid  = threadIdx.x;
    const int lane = tid & 63;
    const int m    = lane >> 1;
    const int par  = lane & 1;
    const bool even = (par == 0);
    const int rA = par * Hn + m;            // i-row (par0) or f-row (par1)
    const int rB = rA + 2 * Hn;             // g-row (par0) or o-row (par1)

    __shared__ __align__(16) float s_xp[2 * CHF];   // 16 KB x staging
    __shared__ __align__(16) float s_gx[2 * GXF];   // 32 KB gx double buffer
    __shared__ __align__(16) float s_ring[RING * NC]; // 41 KB raw-logit ring
    __shared__ int s_prog;   // chunks produced
    __shared__ int s_cons;   // chunks consumed (also: ring availability)

    if (tid == 0) { s_prog = 0; s_cons = 0; }
    __syncthreads();

    const float* __restrict__ xb = x + (size_t)b * Tn * INn;
    float* __restrict__ ob = out + (size_t)b * Tn * NC;

    if (tid >= 64) {
        // ============== producer wave: gx pipeline + softmax drain ==========
        f2 wA[INn / 2], wB[INn / 2];     // 128 VGPR — volatile-pinned loads
        {
            const volatile f2* pA = (const volatile f2*)(W_ih + (size_t)rA * 2 * INn);
            const volatile f2* pB = (const volatile f2*)(W_ih + (size_t)rB * 2 * INn);
            #pragma unroll
            for (int i = 0; i < INn / 2; ++i) { wA[i] = pA[i]; wB[i] = pB[i]; }
        }
        const float biasA = b_ih[rA] + b_hh[rA];
        const float biasB = b_ih[rB] + b_hh[rB];

        int drained = 0;
        // drain ring items [drained, limit): 64 items/pass, one per lane.
        // limit computed from a fresh acquire of s_cons by the caller.
        auto drain_to = [&](int limit) {
            if (limit > RING) limit = RING;
            while (drained < limit) {
                const int d = drained + lane;
                if (d < limit) {
                    const float z0 = s_ring[d * NC + 0];
                    const float z1 = s_ring[d * NC + 1];
                    const float z2 = s_ring[d * NC + 2];
                    const float z3 = s_ring[d * NC + 3];
                    const float z4 = s_ring[d * NC + 4];
                    float bv = z0;                       // exact max, R6 order
                    bv = (z1 > bv) ? z1 : bv;
                    bv = (z2 > bv) ? z2 : bv;
                    bv = (z3 > bv) ? z3 : bv;
                    bv = (z4 > bv) ? z4 : bv;
                    const float se = __expf(z0 - bv) + __expf(z1 - bv)
                                   + __expf(z2 - bv) + __expf(z3 - bv)
                                   + __expf(z4 - bv);   // left-assoc, R6 order
                    const float lse = bv + __logf(se);
                    ob[(size_t)d * NC + 0] = z0 - lse;
                    ob[(size_t)d * NC + 1] = z1 - lse;
                    ob[(size_t)d * NC + 2] = z2 - lse;
                    ob[(size_t)d * NC + 3] = z3 - lse;
                    ob[(size_t)d * NC + 4] = z4 - lse;
                }
                drained += 64;
                if (drained > limit) drained = limit;
            }
        };

        // prefetch x chunks 0,1
        #pragma unroll
        for (int r = 0; r < 8; ++r) gl16(xb + r * 256 + lane * 4, s_xp + r * 256);
        #pragma unroll
        for (int r = 0; r < 8; ++r) gl16(xb + CHF + r * 256 + lane * 4, s_xp + CHF + r * 256);

        for (int q = 0; q < NCHUNK; ++q) {
            if (q == NCHUNK - 1) asm volatile("s_waitcnt vmcnt(0)" ::: "memory");
            else                 asm volatile("s_waitcnt vmcnt(8)" ::: "memory");
            while (ld_acq(&s_cons) < q - 1) {         // gx buf (q&1) free?
                drain_to(ld_acq(&s_cons) * CH - 1);   // use the idle window
            }

            const f2* xc  = (const f2*)(s_xp + (q & 1) * CHF);
            float*    gxd = s_gx + (q & 1) * GXF;
            #pragma unroll 2
            for (int s = 0; s < CH; ++s) {
                const f2* xt2 = xc + s * (INn / 2);
                f2 a0, a1, a2, a3, c0, c1, c2, c3;
                a0 = a1 = a2 = a3 = c0 = c1 = c2 = c3 = (f2)(0.f);
                #pragma unroll
                for (int i = 0; i < INn / 2; i += 4) {
                    const f2 x0 = xt2[i], x1 = xt2[i + 1], x2 = xt2[i + 2], x3 = xt2[i + 3];
                    a0 += wA[i] * x0;     c0 += wB[i] * x0;
                    a1 += wA[i + 1] * x1; c1 += wB[i + 1] * x1;
                    a2 += wA[i + 2] * x2; c2 += wB[i + 2] * x2;
                    a3 += wA[i + 3] * x3; c3 += wB[i + 3] * x3;
                }
                gxd[s * 128 + rA] = biasA + hadd((a0 + a1) + (a2 + a3));
                gxd[s * 128 + rB] = biasB + hadd((c0 + c1) + (c2 + c3));
            }
            if (lane == 0) st_rel(&s_prog, q + 1);   // release: gx drained first
            if (q + 2 < NCHUNK) {                    // refill the freed x buffer
                const float* src = xb + (size_t)(q + 2) * CHF;
                float* dst = s_xp + (q & 1) * CHF;
                #pragma unroll
                for (int r = 0; r < 8; ++r) gl16(src + r * 256 + lane * 4, dst + r * 256);
            }
            drain_to(ld_acq(&s_cons) * CH - 1);      // opportunistic drain
        }
        // final drain: everything up to row RING-1 (=2046)
        while (drained < RING) {
            drain_to(ld_acq(&s_cons) * CH - 1);
        }
    } else {
        // ===================== consumer wave (serial chain) ==================
        // W_hh rows as 32 scalar floats each — volatile-pinned
        float whA_[Hn], whB_[Hn];
        {
            const volatile float* pA = W_hh + (size_t)rA * Hn;
            const volatile float* pB = W_hh + (size_t)(rA + 2 * Hn) * Hn;
            #pragma unroll
            for (int i = 0; i < Hn; ++i) { whA_[i] = pA[i]; whB_[i] = pB[i]; }
        }

        // P[cls] = ( dot(W_ih[rA,64:128], emb[cls]), dot(W_ih[rB,64:128], emb[cls]) )
        f2 P[NC];
        #pragma unroll
        for (int cls = 0; cls < NC; ++cls) {
            float pa = 0.f, pb = 0.f;
            for (int i = 0; i < INn; ++i) {
                const float e = emb[cls * INn + i];
                pa += W_ih[(size_t)rA * 2 * INn + INn + i] * e;
                pb += W_ih[(size_t)(rA + 2 * Hn) * 2 * INn + INn + i] * e;
            }
            f2 v; v.x = pa; v.y = pb; P[cls] = v;
        }

        // per-lane classifier row: class cl = lane % 5 (lanes 0..4 are read)
        const int cl = lane % 5;
        float wfc_[Hn];                  // volatile-pinned
        {
            const volatile float* pf = W_fc + (size_t)cl * Hn;
            #pragma unroll
            for (int i = 0; i < Hn; ++i) wfc_[i] = pf[i];
        }
        const float bfL = b_fc[cl];

        const float zsB  = even ? 2.f : 1.f;   // g: tanh(z) = 2*sig(2z)-1
        const float mulB = even ? 2.f : 1.f;
        const float addB = even ? -1.f : 0.f;

        float cst = 0.f;
        f2 Ps; Ps.x = 0.f; Ps.y = 0.f;
        float h = 0.f;                   // h[m], identical in lanes 2m/2m+1

        // activations + cell update (identical math to proven kernel)
        auto acts = [&](float accA, float accB) -> float {
            const float actA = rcpf(1.f + __expf(-accA));
            const float sgB  = rcpf(1.f + __expf(-zsB * accB));
            const float actB = fmaf(sgB, mulB, addB);

            const float qA = dpp_swap1(actA);
            const float qB = dpp_swap1(actB);
            const float iv = even ? actA : qA;
            const float fv = even ? qA : actA;
            const float gv = even ? actB : qB;
            const float ov = even ? qB : actB;

            cst = fmaf(fv, cst, iv * gv);
            const float e2 = __expf(2.f * cst);
            const float th = 1.f - 2.f * rcpf(e2 + 1.f);
            return ov * th;
        };

        // one step t >= 1: h(t-1) via readlane -> SGPR-operand fmacs.
        // Chain mapping reproduces R6's f2 chains exactly:
        //   chain k = (m>>1)&3, component = m&1, ascending-m visit order,
        //   combine tree ((c0+c1)+(c2+c3)) on x then y, hadd = x+y.
        auto full_step = [&](int t, const float* gxc, int s) {
            const float gA = gxc[s * 128 + rA];
            const float gB = gxc[s * 128 + rB];

            float hs[Hn];
            #pragma unroll
            for (int mm = 0; mm < Hn; ++mm) hs[mm] = rlane(h, 2 * mm);

            float zc[8], aA_[8], aB_[8];
            #pragma unroll
            for (int k = 0; k < 8; ++k) { zc[k] = 0.f; aA_[k] = 0.f; aB_[k] = 0.f; }
            #pragma unroll
            for (int mm = 0; mm < Hn; ++mm) {
                const int k = ((mm >> 1) & 3) * 2 + (mm & 1);
                zc[k]  = fmaf(wfc_[mm], hs[mm], zc[k]);
                aA_[k] = fmaf(whA_[mm], hs[mm], aA_[k]);
                aB_[k] = fmaf(whB_[mm], hs[mm], aB_[k]);
            }
            const float z = ((zc[0] + zc[2]) + (zc[4] + zc[6]))
                          + ((zc[1] + zc[3]) + (zc[5] + zc[7])) + bfL;

            const float p0 = rlane(z, 0), p1 = rlane(z, 1), p2 = rlane(z, 2),
                        p3 = rlane(z, 3), p4 = rlane(z, 4);

            // argmax (first-max-wins, matches np.argmax)
            float bv = p0; int am = 0;
            bool g1 = p1 > bv; bv = g1 ? p1 : bv; am = g1 ? 1 : am;
            bool g2 = p2 > bv; bv = g2 ? p2 : bv; am = g2 ? 2 : am;
            bool g3 = p3 > bv; bv = g3 ? p3 : bv; am = g3 ? 3 : am;
            bool g4 = p4 > bv; bv = g4 ? p4 : bv; am = g4 ? 4 : am;
            Ps = (am == 0) ? P[0] : (am == 1) ? P[1] : (am == 2) ? P[2]
               : (am == 3) ? P[3] : P[4];

            const float hA = ((aA_[0] + aA_[2]) + (aA_[4] + aA_[6]))
                           + ((aA_[1] + aA_[3]) + (aA_[5] + aA_[7]));
            const float hB = ((aB_[0] + aB_[2]) + (aB_[4] + aB_[6]))
                           + ((aB_[1] + aB_[3]) + (aB_[5] + aB_[7]));
            const float accA = gA + hA + Ps.x;
            const float accB = gB + hB + Ps.y;

            h = acts(accA, accB);

            // raw logits -> ring; producer does softmax + store (off-chain)
            if (lane < NC) s_ring[(t - 1) * NC + lane] = z;
        };

        // ---- chunk 0: peel t=0 (h=0, prev=0 -> acc = gx + bias directly) ----
        while (ld_acq(&s_prog) < 1) { }
        {
            const float* gxc = s_gx;
            h = acts(gxc[rA], gxc[rB]);             // t = 0
            for (int s = 1; s < CH; ++s) full_step(s, gxc, s);
            if (lane == 0) st_rel(&s_cons, 1);      // releases ring rows 0..30
        }
        // ---- chunks 1..63 ----
        for (int q = 1; q < NCHUNK; ++q) {
            while (ld_acq(&s_prog) < q + 1) { }
            const float* gxc = s_gx + (q & 1) * GXF;
            for (int s = 0; s < CH; ++s) full_step(q * CH + s, gxc, s);
            if (lane == 0) st_rel(&s_cons, q + 1);
        }
        // ---- epilogue: classifier + softmax + store for t = Tn-1 directly ----
        {
            float hs[Hn];
            #pragma unroll
            for (int mm = 0; mm < Hn; ++mm) hs[mm] = rlane(h, 2 * mm);
            float zc[8];
            #pragma unroll
            for (int k = 0; k < 8; ++k) zc[k] = 0.f;
            #pragma unroll
            for (int mm = 0; mm < Hn; ++mm) {
                const int k = ((mm >> 1) & 3) * 2 + (mm & 1);
                zc[k] = fmaf(wfc_[mm], hs[mm], zc[k]);
            }
            const float z = ((zc[0] + zc[2]) + (zc[4] + zc[6]))
                          + ((zc[1] + zc[3]) + (zc[5] + zc[7])) + bfL;
            const float p0 = rlane(z, 0), p1 = rlane(z, 1), p2 = rlane(z, 2),
                        p3 = rlane(z, 3), p4 = rlane(z, 4);
            float bv = p0;
            bv = (p1 > bv) ? p1 : bv;
            bv = (p2 > bv) ? p2 : bv;
            bv = (p3 > bv) ? p3 : bv;
            bv = (p4 > bv) ? p4 : bv;
            const float se = __expf(p0 - bv) + __expf(p1 - bv) + __expf(p2 - bv)
                           + __expf(p3 - bv) + __expf(p4 - bv);
            const float lse = bv + __logf(se);
            if (lane < NC) {
                float pv = p0;
                pv = (lane == 1) ? p1 : pv;
                pv = (lane == 2) ? p2 : pv;
                pv = (lane == 3) ? p3 : pv;
                pv = (lane == 4) ? p4 : pv;
                ob[(size_t)(Tn - 1) * NC + lane] = pv - lse;
            }
        }
    }
}

} // namespace

extern "C" void kernel_launch(void* const* d_in, const int* in_sizes, int n_in,
                              void* d_out, int out_size, void* d_ws, size_t ws_size,
                              hipStream_t stream) {
    (void)in_sizes; (void)n_in; (void)d_ws; (void)ws_size; (void)out_size;
    const float* x    = (const float*)d_in[0];
    // d_in[1] x_lengths (all == T), d_in[2] edge_list: unused
    const float* W_ih = (const float*)d_in[3];
    const float* W_hh = (const float*)d_in[4];
    const float* b_ih = (const float*)d_in[5];
    const float* b_hh = (const float*)d_in[6];
    const float* W_fc = (const float*)d_in[7];
    const float* b_fc = (const float*)d_in[8];
    const float* emb  = (const float*)d_in[9];
    float* out = (float*)d_out;

    hipLaunchKernelGGL(ar_decode, dim3(256), dim3(128), 0, stream,
                       x, W_ih, W_hh, b_ih, b_hh, W_fc, b_fc, emb, out);
}